// Round 18
// baseline (875.810 us; speedup 1.0000x reference)
//
#include <hip/hip_runtime.h>
#include <hip/hip_bf16.h>

#define HDIM 2048
#define IDIM 1024
#define NEXP 16
#define TTOK 4096   // B*S tokens
#define KTOP 2

typedef __attribute__((ext_vector_type(4))) float f32x4;
typedef __attribute__((ext_vector_type(8))) short bf16x8;
typedef __attribute__((ext_vector_type(4))) unsigned short u16x4;

__device__ __forceinline__ unsigned short f2b(float f) {
  __hip_bfloat16 h = __float2bfloat16(f);
  return *reinterpret_cast<unsigned short*>(&h);
}

// phase-boundary primitives
#define WAIT_VM0()   { asm volatile("s_waitcnt vmcnt(0)" ::: "memory"); __builtin_amdgcn_sched_barrier(0); }
#define WAIT_LGKM0() { asm volatile("s_waitcnt lgkmcnt(0)" ::: "memory"); __builtin_amdgcn_sched_barrier(0); }
#define BARRIER()    { __builtin_amdgcn_s_barrier(); __builtin_amdgcn_sched_barrier(0); }

// byte offset in a [rows][64 bf16] LDS tile (128 B/row), hash-swizzled.
__device__ __forceinline__ int swzh(int row, int kb) {
  return row * 128 + (kb ^ (((row ^ (row >> 3)) & 7) << 4));
}
__device__ __forceinline__ int rowhash(int r) { return (r ^ (r >> 3)) & 7; }

// ---------------------------------------------------------------- gating + x->bf16 (fused)
__global__ __launch_bounds__(256) void gating_kernel(const float* __restrict__ x,
                                                     const float* __restrict__ gw,
                                                     unsigned short* __restrict__ xb,
                                                     float* __restrict__ tw,
                                                     int2* __restrict__ tidx) {
  const int wv = threadIdx.x >> 6;
  const int lane = threadIdx.x & 63;
  const int t = blockIdx.x * 4 + wv;

  float acc[NEXP];
#pragma unroll
  for (int e = 0; e < NEXP; ++e) acc[e] = 0.f;

  const float* xr = x + (size_t)t * HDIM;
  unsigned short* xbr = xb + (size_t)t * HDIM;
#pragma unroll
  for (int j = 0; j < HDIM / 256; ++j) {
    f32x4 xv = *reinterpret_cast<const f32x4*>(xr + j * 256 + lane * 4);
    u16x4 o;
    o[0] = f2b(xv[0]); o[1] = f2b(xv[1]); o[2] = f2b(xv[2]); o[3] = f2b(xv[3]);
    *reinterpret_cast<u16x4*>(xbr + j * 256 + lane * 4) = o;
#pragma unroll
    for (int e = 0; e < NEXP; ++e) {
      f32x4 gv = *reinterpret_cast<const f32x4*>(gw + (size_t)e * HDIM + j * 256 + lane * 4);
      acc[e] = fmaf(xv[0], gv[0], acc[e]);
      acc[e] = fmaf(xv[1], gv[1], acc[e]);
      acc[e] = fmaf(xv[2], gv[2], acc[e]);
      acc[e] = fmaf(xv[3], gv[3], acc[e]);
    }
  }
#pragma unroll
  for (int e = 0; e < NEXP; ++e) {
#pragma unroll
    for (int off = 32; off; off >>= 1) acc[e] += __shfl_xor(acc[e], off);
  }
  // top-2 (ties -> lowest index, matching lax.top_k)
  int i0 = 0; float s0 = acc[0];
#pragma unroll
  for (int e = 1; e < NEXP; ++e) { if (acc[e] > s0) { s0 = acc[e]; i0 = e; } }
  int i1 = -1; float s1 = -1e30f;
#pragma unroll
  for (int e = 0; e < NEXP; ++e) { if (e != i0 && acc[e] > s1) { s1 = acc[e]; i1 = e; } }

  if (lane == 0) {
    float r = __expf(s1 - s0);          // <= 1
    float w0 = 1.f / (1.f + r);
    float w1 = r / (1.f + r);
    tw[t * 2 + 0] = w0;
    tw[t * 2 + 1] = w1;
    tidx[t] = make_int2(i0, i1);
  }
}

// ---------------------------------------------------------------- build lists
__global__ __launch_bounds__(1024) void build_lists_kernel(const int2* __restrict__ tidx,
                                                           int* __restrict__ counts,
                                                           int* __restrict__ list) {
  __shared__ int cur[NEXP];
  const int tid = threadIdx.x;
  if (tid < NEXP) cur[tid] = 0;
  __syncthreads();
  for (int t = tid; t < TTOK; t += 1024) {
    int2 ii = tidx[t];
    int p = atomicAdd(&cur[ii.x], 1);
    list[ii.x * TTOK + p] = t * 2;
    int q = atomicAdd(&cur[ii.y], 1);
    list[ii.y * TTOK + q] = t * 2 + 1;
  }
  __syncthreads();
  if (tid < NEXP) counts[tid] = cur[tid];
}

// ---------------------------------------------------------------- GEMM1  (BM=128, BN=128, BK=64)
// act[slot, :] = silu(x@wg) * (x@wu) * weight
// 512 threads / 8 waves = 2m x 4n of R14's PROVEN 64m x 32n dual-type wave
// tile; per-thread workload identical to R14 (acc 64 VGPR, 8 B-stage loads,
// uniform staging — no divergence). A-traffic halves vs R14 (8 n-blocks).
__global__ __launch_bounds__(512, 4) void gemm1_kernel(
    const unsigned short* __restrict__ xb, const float* __restrict__ wg,
    const float* __restrict__ wu, const int* __restrict__ counts,
    const int* __restrict__ list, const float* __restrict__ tw,
    unsigned short* __restrict__ act) {
  const int bid = blockIdx.x;
  const int e = (bid & 7) + 8 * ((bid >> 3) & 1);
  const int rest = bid >> 4;               // 0..63
  const int mblk = rest & 7;               // m fastest: same-n blocks adjacent
  const int nblk = rest >> 3;              // 0..7
  const int cnt = counts[e];
  const int m0 = mblk * 128;
  if (m0 >= cnt) return;
  const int n0 = nblk * 128;

  __shared__ __align__(16) char As[2 * 128 * 128];  // 2 x [128 m][64 k] bf16, 32 KB
  __shared__ __align__(16) char Bgs[128 * 128];     // [128 n][64 k] bf16, 16 KB
  __shared__ __align__(16) char Bus[128 * 128];     // 16 KB  (total 65 KB)
  __shared__ int slot_s[128];
  __shared__ float ws_s[128];

  const int tid = threadIdx.x;
  if (tid < 128) {
    int mr = m0 + tid;
    int mrc = mr < cnt ? mr : cnt - 1;
    int slot = list[e * TTOK + mrc];
    slot_s[tid] = slot;
    ws_s[tid] = tw[slot];
  }
  __syncthreads();

  const int lane = tid & 63;
  const int wv = tid >> 6;                 // 0..7

  // A staging: 2 DMA issues; issue i covers rows [i*64 + wv*8 + lane>>3].
  const unsigned short* agsrc[2];
#pragma unroll
  for (int i = 0; i < 2; ++i) {
    const int r = i * 64 + wv * 8 + (lane >> 3);
    agsrc[i] = xb + (size_t)(slot_s[r] >> 1) * HDIM + ((lane & 7) ^ rowhash(r)) * 8;
  }
  const int adst = wv * 1024;              // + i*8192 + buf

  // B staging: thread owns 4k x 4n; 512 threads cover 64k x 128n (g and u).
  const int nq4 = (tid & 31) * 4;          // n 0..124
  const int kg4 = (tid >> 5) * 4;          // k 0..60
  const float* bgp = wg + (size_t)e * (HDIM * IDIM) + (size_t)kg4 * IDIM + n0 + nq4;
  const float* bup = wu + (size_t)e * (HDIM * IDIM) + (size_t)kg4 * IDIM + n0 + nq4;

  // fragment params: wave tile 64m x 32n (g and u) — R14's proven shape.
  const int wm = (wv >> 2) * 64;           // 0 or 64
  const int wn = (wv & 3) * 32;            // 0,32,64,96
  const int fr = lane & 15;
  const int fk = lane >> 4;

  f32x4 accg[4][2], accu[4][2];
#pragma unroll
  for (int mi = 0; mi < 4; ++mi)
#pragma unroll
    for (int ni = 0; ni < 2; ++ni) {
      accg[mi][ni] = (f32x4){0.f, 0.f, 0.f, 0.f};
      accu[mi][ni] = (f32x4){0.f, 0.f, 0.f, 0.f};
    }

  f32x4 rg[4], ru[4];
  auto stageA = [&](int kelem, int bufo) {
#pragma unroll
    for (int i = 0; i < 2; ++i)
      __builtin_amdgcn_global_load_lds(
          (const __attribute__((address_space(1))) unsigned int*)(agsrc[i] + kelem),
          (__attribute__((address_space(3))) unsigned int*)(As + bufo + adst + i * 8192),
          16, 0, 0);
  };
  auto loadB = [&](int k) {
#pragma unroll
    for (int i = 0; i < 4; ++i) {
      rg[i] = *reinterpret_cast<const f32x4*>(bgp + (size_t)(k + i) * IDIM);
      ru[i] = *reinterpret_cast<const f32x4*>(bup + (size_t)(k + i) * IDIM);
    }
  };
  auto writeB = [&]() {
#pragma unroll
    for (int c = 0; c < 4; ++c) {
      u16x4 tg, tu;
#pragma unroll
      for (int i = 0; i < 4; ++i) { tg[i] = f2b(rg[i][c]); tu[i] = f2b(ru[i][c]); }
      const int wb = swzh(nq4 + c, kg4 * 2);
      *reinterpret_cast<u16x4*>(Bgs + wb) = tg;
      *reinterpret_cast<u16x4*>(Bus + wb) = tu;
    }
  };
  auto compute = [&](int abuf) {
#pragma unroll
    for (int ks = 0; ks < 2; ++ks) {
      const int kb = ks * 64 + fk * 16;
      bf16x8 a[4], bg[2], bu[2];
#pragma unroll
      for (int mi = 0; mi < 4; ++mi)
        a[mi] = *reinterpret_cast<const bf16x8*>(As + abuf + swzh(wm + mi * 16 + fr, kb));
#pragma unroll
      for (int ni = 0; ni < 2; ++ni) {
        bg[ni] = *reinterpret_cast<const bf16x8*>(Bgs + swzh(wn + ni * 16 + fr, kb));
        bu[ni] = *reinterpret_cast<const bf16x8*>(Bus + swzh(wn + ni * 16 + fr, kb));
      }
      __builtin_amdgcn_s_setprio(1);
#pragma unroll
      for (int mi = 0; mi < 4; ++mi)
#pragma unroll
        for (int ni = 0; ni < 2; ++ni) {
          accg[mi][ni] = __builtin_amdgcn_mfma_f32_16x16x32_bf16(a[mi], bg[ni], accg[mi][ni], 0, 0, 0);
          accu[mi][ni] = __builtin_amdgcn_mfma_f32_16x16x32_bf16(a[mi], bu[ni], accu[mi][ni], 0, 0, 0);
        }
      __builtin_amdgcn_s_setprio(0);
    }
  };

  stageA(0, 0);
  stageA(64, 16384);
  loadB(0);
  WAIT_VM0();
  writeB();
  WAIT_LGKM0();
  BARRIER();
  loadB(64);

  const int NT = HDIM / 64;  // 32
#pragma unroll 1
  for (int t = 0; t < NT; ++t) {
    compute((t & 1) * 16384);
    WAIT_LGKM0();
    BARRIER();
    if (t + 1 < NT) {
      WAIT_VM0();
      writeB();
    }
    if (t + 2 < NT) stageA((t + 2) * 64, (t & 1) * 16384);
    WAIT_LGKM0();
    BARRIER();
    if (t + 2 < NT) loadB((t + 2) * 64);
  }

  // epilogue: silu(g)*u*w -> bf16 act
#pragma unroll
  for (int mi = 0; mi < 4; ++mi)
#pragma unroll
    for (int ni = 0; ni < 2; ++ni)
#pragma unroll
      for (int r = 0; r < 4; ++r) {
        const int trow = wm + mi * 16 + fk * 4 + r;
        if (m0 + trow < cnt) {
          const int col = n0 + wn + ni * 16 + fr;
          const float g = accg[mi][ni][r];
          const float u = accu[mi][ni][r];
          const float a = (g / (1.f + __expf(-g))) * u * ws_s[trow];
          act[(size_t)slot_s[trow] * IDIM + col] = f2b(a);
        }
      }
}

// ---------------------------------------------------------------- GEMM2  (BM=128, BN=256, BK=64)
// out[token, :] += act[slot, :] @ wd[e]
// 512 threads / 8 waves = 2m x 4n of R14 gemm2's proven 64m x 64n wave tile.
__global__ __launch_bounds__(512, 4) void gemm2_kernel(
    const unsigned short* __restrict__ act, const float* __restrict__ wd,
    const int* __restrict__ counts, const int* __restrict__ list,
    float* __restrict__ out) {
  const int bid = blockIdx.x;
  const int e = (bid & 7) + 8 * ((bid >> 3) & 1);
  const int rest = bid >> 4;               // 0..63
  const int mblk = rest & 7;
  const int nblk = rest >> 3;              // 0..7
  const int cnt = counts[e];
  const int m0 = mblk * 128;
  if (m0 >= cnt) return;
  const int n0 = nblk * 256;

  __shared__ __align__(16) char As[2 * 128 * 128];  // 32 KB
  __shared__ __align__(16) char Bs[256 * 128];      // [256 n][64 k], 32 KB
  __shared__ int slot_s[128];

  const int tid = threadIdx.x;
  if (tid < 128) {
    int mr = m0 + tid;
    int mrc = mr < cnt ? mr : cnt - 1;
    slot_s[tid] = list[e * TTOK + mrc];
  }
  __syncthreads();

  const int lane = tid & 63;
  const int wv = tid >> 6;

  const unsigned short* agsrc[2];
#pragma unroll
  for (int i = 0; i < 2; ++i) {
    const int r = i * 64 + wv * 8 + (lane >> 3);
    agsrc[i] = act + (size_t)slot_s[r] * IDIM + ((lane & 7) ^ rowhash(r)) * 8;
  }
  const int adst = wv * 1024;

  // B staging: thread owns 4k x 4n at rows kg4+32h; 512 threads cover 64k x 256n.
  const int nq4 = (tid & 63) * 4;          // n 0..252
  const int kg4 = ((tid >> 6) & 7) * 4;    // k 0..28 (+32 for h=1)
  const float* bdp = wd + (size_t)e * (IDIM * HDIM) + (size_t)kg4 * HDIM + n0 + nq4;

  const int wm = (wv >> 2) * 64;           // 0 or 64
  const int wn = (wv & 3) * 64;            // 0,64,128,192
  const int fr = lane & 15;
  const int fk = lane >> 4;

  f32x4 acc[4][4];
#pragma unroll
  for (int mi = 0; mi < 4; ++mi)
#pragma unroll
    for (int ni = 0; ni < 4; ++ni) acc[mi][ni] = (f32x4){0.f, 0.f, 0.f, 0.f};

  f32x4 rb[2][4];
  auto stageA = [&](int kelem, int bufo) {
#pragma unroll
    for (int i = 0; i < 2; ++i)
      __builtin_amdgcn_global_load_lds(
          (const __attribute__((address_space(1))) unsigned int*)(agsrc[i] + kelem),
          (__attribute__((address_space(3))) unsigned int*)(As + bufo + adst + i * 8192),
          16, 0, 0);
  };
  auto loadB = [&](int k) {
#pragma unroll
    for (int h = 0; h < 2; ++h)
#pragma unroll
      for (int i = 0; i < 4; ++i)
        rb[h][i] = *reinterpret_cast<const f32x4*>(bdp + (size_t)(k + 32 * h + i) * HDIM);
  };
  auto writeB = [&]() {
#pragma unroll
    for (int h = 0; h < 2; ++h)
#pragma unroll
      for (int c = 0; c < 4; ++c) {
        u16x4 tb;
#pragma unroll
        for (int i = 0; i < 4; ++i) tb[i] = f2b(rb[h][i][c]);
        *reinterpret_cast<u16x4*>(Bs + swzh(nq4 + c, (kg4 + 32 * h) * 2)) = tb;
      }
  };
  auto compute = [&](int abuf) {
#pragma unroll
    for (int ks = 0; ks < 2; ++ks) {
      const int kb = ks * 64 + fk * 16;
      bf16x8 a[4], b[4];
#pragma unroll
      for (int mi = 0; mi < 4; ++mi)
        a[mi] = *reinterpret_cast<const bf16x8*>(As + abuf + swzh(wm + mi * 16 + fr, kb));
#pragma unroll
      for (int ni = 0; ni < 4; ++ni)
        b[ni] = *reinterpret_cast<const bf16x8*>(Bs + swzh(wn + ni * 16 + fr, kb));
      __builtin_amdgcn_s_setprio(1);
#pragma unroll
      for (int mi = 0; mi < 4; ++mi)
#pragma unroll
        for (int ni = 0; ni < 4; ++ni)
          acc[mi][ni] = __builtin_amdgcn_mfma_f32_16x16x32_bf16(a[mi], b[ni], acc[mi][ni], 0, 0, 0);
      __builtin_amdgcn_s_setprio(0);
    }
  };

  stageA(0, 0);
  stageA(64, 16384);
  loadB(0);
  WAIT_VM0();
  writeB();
  WAIT_LGKM0();
  BARRIER();
  loadB(64);

  const int NT = IDIM / 64;  // 16
#pragma unroll 1
  for (int t = 0; t < NT; ++t) {
    compute((t & 1) * 16384);
    WAIT_LGKM0();
    BARRIER();
    if (t + 1 < NT) {
      WAIT_VM0();
      writeB();
    }
    if (t + 2 < NT) stageA((t + 2) * 64, (t & 1) * 16384);
    WAIT_LGKM0();
    BARRIER();
    if (t + 2 < NT) loadB((t + 2) * 64);
  }

#pragma unroll
  for (int mi = 0; mi < 4; ++mi)
#pragma unroll
    for (int ni = 0; ni < 4; ++ni)
#pragma unroll
      for (int r = 0; r < 4; ++r) {
        const int trow = wm + mi * 16 + fk * 4 + r;
        if (m0 + trow < cnt) {
          const int t = slot_s[trow] >> 1;
          const int col = n0 + wn + ni * 16 + fr;
          atomicAdd(&out[(size_t)t * HDIM + col], acc[mi][ni][r]);
        }
      }
}

// ---------------------------------------------------------------- launch
extern "C" void kernel_launch(void* const* d_in, const int* in_sizes, int n_in,
                              void* d_out, int out_size, void* d_ws, size_t ws_size,
                              hipStream_t stream) {
  const float* x = (const float*)d_in[0];
  const float* gate_w = (const float*)d_in[1];
  const float* wg = (const float*)d_in[2];
  const float* wu = (const float*)d_in[3];
  const float* wd = (const float*)d_in[4];
  float* out = (float*)d_out;

  char* w = (char*)d_ws;
  size_t off = 0;
  unsigned short* xb = (unsigned short*)(w + off); off += (size_t)TTOK * HDIM * 2;
  unsigned short* act = (unsigned short*)(w + off); off += (size_t)TTOK * KTOP * IDIM * 2;
  float* tw = (float*)(w + off); off += (size_t)TTOK * KTOP * 4;
  int2* tidx = (int2*)(w + off); off += (size_t)TTOK * 8;
  int* counts = (int*)(w + off); off += 256;
  int* list = (int*)(w + off); off += (size_t)NEXP * TTOK * 4;

  hipMemsetAsync(out, 0, (size_t)TTOK * HDIM * sizeof(float), stream);
  gating_kernel<<<TTOK / 4, 256, 0, stream>>>(x, gate_w, xb, tw, tidx);
  build_lists_kernel<<<1, 1024, 0, stream>>>(tidx, counts, list);
  // gemm1: 16 e x 8 m x 8 n = 1024 blocks (XCD-clustered decode in-kernel)
  gemm1_kernel<<<1024, 512, 0, stream>>>(xb, wg, wu, counts, list, tw, act);
  // gemm2: 16 e x 8 m x 8 n = 1024 blocks
  gemm2_kernel<<<1024, 512, 0, stream>>>(act, wd, counts, list, out);
}

// Round 19
// 421.145 us; speedup vs baseline: 2.0796x; 2.0796x over previous
//
#include <hip/hip_runtime.h>
#include <hip/hip_bf16.h>

#define HDIM 2048
#define IDIM 1024
#define NEXP 16
#define TTOK 4096   // B*S tokens
#define KTOP 2

typedef __attribute__((ext_vector_type(4))) float f32x4;
typedef __attribute__((ext_vector_type(8))) short bf16x8;
typedef __attribute__((ext_vector_type(4))) unsigned short u16x4;

__device__ __forceinline__ unsigned short f2b(float f) {
  __hip_bfloat16 h = __float2bfloat16(f);
  return *reinterpret_cast<unsigned short*>(&h);
}

// phase-boundary primitives
#define WAIT_VM0()   { asm volatile("s_waitcnt vmcnt(0)" ::: "memory"); __builtin_amdgcn_sched_barrier(0); }
#define WAIT_LGKM0() { asm volatile("s_waitcnt lgkmcnt(0)" ::: "memory"); __builtin_amdgcn_sched_barrier(0); }
#define BARRIER()    { __builtin_amdgcn_s_barrier(); __builtin_amdgcn_sched_barrier(0); }

// byte offset in a [rows][64 bf16] LDS tile (128 B/row), hash-swizzled.
__device__ __forceinline__ int swzh(int row, int kb) {
  return row * 128 + (kb ^ (((row ^ (row >> 3)) & 7) << 4));
}
__device__ __forceinline__ int rowhash(int r) { return (r ^ (r >> 3)) & 7; }

// ---------------------------------------------------------------- gating + x->bf16 (fused)
__global__ __launch_bounds__(256) void gating_kernel(const float* __restrict__ x,
                                                     const float* __restrict__ gw,
                                                     unsigned short* __restrict__ xb,
                                                     float* __restrict__ tw,
                                                     int2* __restrict__ tidx) {
  const int wv = threadIdx.x >> 6;
  const int lane = threadIdx.x & 63;
  const int t = blockIdx.x * 4 + wv;

  float acc[NEXP];
#pragma unroll
  for (int e = 0; e < NEXP; ++e) acc[e] = 0.f;

  const float* xr = x + (size_t)t * HDIM;
  unsigned short* xbr = xb + (size_t)t * HDIM;
#pragma unroll
  for (int j = 0; j < HDIM / 256; ++j) {
    f32x4 xv = *reinterpret_cast<const f32x4*>(xr + j * 256 + lane * 4);
    u16x4 o;
    o[0] = f2b(xv[0]); o[1] = f2b(xv[1]); o[2] = f2b(xv[2]); o[3] = f2b(xv[3]);
    *reinterpret_cast<u16x4*>(xbr + j * 256 + lane * 4) = o;
#pragma unroll
    for (int e = 0; e < NEXP; ++e) {
      f32x4 gv = *reinterpret_cast<const f32x4*>(gw + (size_t)e * HDIM + j * 256 + lane * 4);
      acc[e] = fmaf(xv[0], gv[0], acc[e]);
      acc[e] = fmaf(xv[1], gv[1], acc[e]);
      acc[e] = fmaf(xv[2], gv[2], acc[e]);
      acc[e] = fmaf(xv[3], gv[3], acc[e]);
    }
  }
#pragma unroll
  for (int e = 0; e < NEXP; ++e) {
#pragma unroll
    for (int off = 32; off; off >>= 1) acc[e] += __shfl_xor(acc[e], off);
  }
  // top-2 (ties -> lowest index, matching lax.top_k)
  int i0 = 0; float s0 = acc[0];
#pragma unroll
  for (int e = 1; e < NEXP; ++e) { if (acc[e] > s0) { s0 = acc[e]; i0 = e; } }
  int i1 = -1; float s1 = -1e30f;
#pragma unroll
  for (int e = 0; e < NEXP; ++e) { if (e != i0 && acc[e] > s1) { s1 = acc[e]; i1 = e; } }

  if (lane == 0) {
    float r = __expf(s1 - s0);          // <= 1
    float w0 = 1.f / (1.f + r);
    float w1 = r / (1.f + r);
    tw[t * 2 + 0] = w0;
    tw[t * 2 + 1] = w1;
    tidx[t] = make_int2(i0, i1);
  }
}

// ---------------------------------------------------------------- build lists
__global__ __launch_bounds__(1024) void build_lists_kernel(const int2* __restrict__ tidx,
                                                           int* __restrict__ counts,
                                                           int* __restrict__ list) {
  __shared__ int cur[NEXP];
  const int tid = threadIdx.x;
  if (tid < NEXP) cur[tid] = 0;
  __syncthreads();
  for (int t = tid; t < TTOK; t += 1024) {
    int2 ii = tidx[t];
    int p = atomicAdd(&cur[ii.x], 1);
    list[ii.x * TTOK + p] = t * 2;
    int q = atomicAdd(&cur[ii.y], 1);
    list[ii.y * TTOK + q] = t * 2 + 1;
  }
  __syncthreads();
  if (tid < NEXP) counts[tid] = cur[tid];
}

// ---------------------------------------------------------------- GEMM1  (BM=128, BN=128, BK=64)
// act[slot, :] = silu(x@wg) * (x@wu) * weight
// 512 threads / 8 waves = 2m x 4n of R14's proven 64m x 32n dual-type wave
// tile. launch_bounds(512,2): VGPR cap >= 128 so the ~90 live regs FIT —
// (512,4) capped at 64 and spilled 390 MB/dispatch (R16/R18 failure cause).
__global__ __launch_bounds__(512, 2) void gemm1_kernel(
    const unsigned short* __restrict__ xb, const float* __restrict__ wg,
    const float* __restrict__ wu, const int* __restrict__ counts,
    const int* __restrict__ list, const float* __restrict__ tw,
    unsigned short* __restrict__ act) {
  const int bid = blockIdx.x;
  const int e = (bid & 7) + 8 * ((bid >> 3) & 1);
  const int rest = bid >> 4;               // 0..63
  const int mblk = rest & 7;               // m fastest: same-n blocks adjacent
  const int nblk = rest >> 3;              // 0..7
  const int cnt = counts[e];
  const int m0 = mblk * 128;
  if (m0 >= cnt) return;
  const int n0 = nblk * 128;

  __shared__ __align__(16) char As[2 * 128 * 128];  // 2 x [128 m][64 k] bf16, 32 KB
  __shared__ __align__(16) char Bgs[128 * 128];     // [128 n][64 k] bf16, 16 KB
  __shared__ __align__(16) char Bus[128 * 128];     // 16 KB  (total 65 KB)
  __shared__ int slot_s[128];
  __shared__ float ws_s[128];

  const int tid = threadIdx.x;
  if (tid < 128) {
    int mr = m0 + tid;
    int mrc = mr < cnt ? mr : cnt - 1;
    int slot = list[e * TTOK + mrc];
    slot_s[tid] = slot;
    ws_s[tid] = tw[slot];
  }
  __syncthreads();

  const int lane = tid & 63;
  const int wv = tid >> 6;                 // 0..7

  // A staging: 2 DMA issues; issue i covers rows [i*64 + wv*8 + lane>>3].
  const unsigned short* agsrc[2];
#pragma unroll
  for (int i = 0; i < 2; ++i) {
    const int r = i * 64 + wv * 8 + (lane >> 3);
    agsrc[i] = xb + (size_t)(slot_s[r] >> 1) * HDIM + ((lane & 7) ^ rowhash(r)) * 8;
  }
  const int adst = wv * 1024;              // + i*8192 + buf

  // B staging: thread owns 4k x 4n; 512 threads cover 64k x 128n (g and u).
  const int nq4 = (tid & 31) * 4;          // n 0..124
  const int kg4 = (tid >> 5) * 4;          // k 0..60
  const float* bgp = wg + (size_t)e * (HDIM * IDIM) + (size_t)kg4 * IDIM + n0 + nq4;
  const float* bup = wu + (size_t)e * (HDIM * IDIM) + (size_t)kg4 * IDIM + n0 + nq4;

  // fragment params: wave tile 64m x 32n (g and u) — R14's proven shape.
  const int wm = (wv >> 2) * 64;           // 0 or 64
  const int wn = (wv & 3) * 32;            // 0,32,64,96
  const int fr = lane & 15;
  const int fk = lane >> 4;

  f32x4 accg[4][2], accu[4][2];
#pragma unroll
  for (int mi = 0; mi < 4; ++mi)
#pragma unroll
    for (int ni = 0; ni < 2; ++ni) {
      accg[mi][ni] = (f32x4){0.f, 0.f, 0.f, 0.f};
      accu[mi][ni] = (f32x4){0.f, 0.f, 0.f, 0.f};
    }

  f32x4 rg[4], ru[4];
  auto stageA = [&](int kelem, int bufo) {
#pragma unroll
    for (int i = 0; i < 2; ++i)
      __builtin_amdgcn_global_load_lds(
          (const __attribute__((address_space(1))) unsigned int*)(agsrc[i] + kelem),
          (__attribute__((address_space(3))) unsigned int*)(As + bufo + adst + i * 8192),
          16, 0, 0);
  };
  auto loadB = [&](int k) {
#pragma unroll
    for (int i = 0; i < 4; ++i) {
      rg[i] = *reinterpret_cast<const f32x4*>(bgp + (size_t)(k + i) * IDIM);
      ru[i] = *reinterpret_cast<const f32x4*>(bup + (size_t)(k + i) * IDIM);
    }
  };
  auto writeB = [&]() {
#pragma unroll
    for (int c = 0; c < 4; ++c) {
      u16x4 tg, tu;
#pragma unroll
      for (int i = 0; i < 4; ++i) { tg[i] = f2b(rg[i][c]); tu[i] = f2b(ru[i][c]); }
      const int wb = swzh(nq4 + c, kg4 * 2);
      *reinterpret_cast<u16x4*>(Bgs + wb) = tg;
      *reinterpret_cast<u16x4*>(Bus + wb) = tu;
    }
  };
  auto compute = [&](int abuf) {
#pragma unroll
    for (int ks = 0; ks < 2; ++ks) {
      const int kb = ks * 64 + fk * 16;
      bf16x8 a[4], bg[2], bu[2];
#pragma unroll
      for (int mi = 0; mi < 4; ++mi)
        a[mi] = *reinterpret_cast<const bf16x8*>(As + abuf + swzh(wm + mi * 16 + fr, kb));
#pragma unroll
      for (int ni = 0; ni < 2; ++ni) {
        bg[ni] = *reinterpret_cast<const bf16x8*>(Bgs + swzh(wn + ni * 16 + fr, kb));
        bu[ni] = *reinterpret_cast<const bf16x8*>(Bus + swzh(wn + ni * 16 + fr, kb));
      }
      __builtin_amdgcn_s_setprio(1);
#pragma unroll
      for (int mi = 0; mi < 4; ++mi)
#pragma unroll
        for (int ni = 0; ni < 2; ++ni) {
          accg[mi][ni] = __builtin_amdgcn_mfma_f32_16x16x32_bf16(a[mi], bg[ni], accg[mi][ni], 0, 0, 0);
          accu[mi][ni] = __builtin_amdgcn_mfma_f32_16x16x32_bf16(a[mi], bu[ni], accu[mi][ni], 0, 0, 0);
        }
      __builtin_amdgcn_s_setprio(0);
    }
  };

  stageA(0, 0);
  stageA(64, 16384);
  loadB(0);
  WAIT_VM0();
  writeB();
  WAIT_LGKM0();
  BARRIER();
  loadB(64);

  const int NT = HDIM / 64;  // 32
#pragma unroll 1
  for (int t = 0; t < NT; ++t) {
    compute((t & 1) * 16384);
    WAIT_LGKM0();
    BARRIER();
    if (t + 1 < NT) {
      WAIT_VM0();
      writeB();
    }
    if (t + 2 < NT) stageA((t + 2) * 64, (t & 1) * 16384);
    WAIT_LGKM0();
    BARRIER();
    if (t + 2 < NT) loadB((t + 2) * 64);
  }

  // epilogue: silu(g)*u*w -> bf16 act
#pragma unroll
  for (int mi = 0; mi < 4; ++mi)
#pragma unroll
    for (int ni = 0; ni < 2; ++ni)
#pragma unroll
      for (int r = 0; r < 4; ++r) {
        const int trow = wm + mi * 16 + fk * 4 + r;
        if (m0 + trow < cnt) {
          const int col = n0 + wn + ni * 16 + fr;
          const float g = accg[mi][ni][r];
          const float u = accu[mi][ni][r];
          const float a = (g / (1.f + __expf(-g))) * u * ws_s[trow];
          act[(size_t)slot_s[trow] * IDIM + col] = f2b(a);
        }
      }
}

// ---------------------------------------------------------------- GEMM2  (BM=128, BN=256, BK=64)
// out[token, :] += act[slot, :] @ wd[e]
// 512 threads / 8 waves = 2m x 4n of R14 gemm2's proven 64m x 64n wave tile.
__global__ __launch_bounds__(512, 2) void gemm2_kernel(
    const unsigned short* __restrict__ act, const float* __restrict__ wd,
    const int* __restrict__ counts, const int* __restrict__ list,
    float* __restrict__ out) {
  const int bid = blockIdx.x;
  const int e = (bid & 7) + 8 * ((bid >> 3) & 1);
  const int rest = bid >> 4;               // 0..63
  const int mblk = rest & 7;
  const int nblk = rest >> 3;              // 0..7
  const int cnt = counts[e];
  const int m0 = mblk * 128;
  if (m0 >= cnt) return;
  const int n0 = nblk * 256;

  __shared__ __align__(16) char As[2 * 128 * 128];  // 32 KB
  __shared__ __align__(16) char Bs[256 * 128];      // [256 n][64 k], 32 KB
  __shared__ int slot_s[128];

  const int tid = threadIdx.x;
  if (tid < 128) {
    int mr = m0 + tid;
    int mrc = mr < cnt ? mr : cnt - 1;
    slot_s[tid] = list[e * TTOK + mrc];
  }
  __syncthreads();

  const int lane = tid & 63;
  const int wv = tid >> 6;

  const unsigned short* agsrc[2];
#pragma unroll
  for (int i = 0; i < 2; ++i) {
    const int r = i * 64 + wv * 8 + (lane >> 3);
    agsrc[i] = act + (size_t)slot_s[r] * IDIM + ((lane & 7) ^ rowhash(r)) * 8;
  }
  const int adst = wv * 1024;

  // B staging: thread owns 4k x 4n at rows kg4+32h; 512 threads cover 64k x 256n.
  const int nq4 = (tid & 63) * 4;          // n 0..252
  const int kg4 = ((tid >> 6) & 7) * 4;    // k 0..28 (+32 for h=1)
  const float* bdp = wd + (size_t)e * (IDIM * HDIM) + (size_t)kg4 * HDIM + n0 + nq4;

  const int wm = (wv >> 2) * 64;           // 0 or 64
  const int wn = (wv & 3) * 64;            // 0,64,128,192
  const int fr = lane & 15;
  const int fk = lane >> 4;

  f32x4 acc[4][4];
#pragma unroll
  for (int mi = 0; mi < 4; ++mi)
#pragma unroll
    for (int ni = 0; ni < 4; ++ni) acc[mi][ni] = (f32x4){0.f, 0.f, 0.f, 0.f};

  f32x4 rb[2][4];
  auto stageA = [&](int kelem, int bufo) {
#pragma unroll
    for (int i = 0; i < 2; ++i)
      __builtin_amdgcn_global_load_lds(
          (const __attribute__((address_space(1))) unsigned int*)(agsrc[i] + kelem),
          (__attribute__((address_space(3))) unsigned int*)(As + bufo + adst + i * 8192),
          16, 0, 0);
  };
  auto loadB = [&](int k) {
#pragma unroll
    for (int h = 0; h < 2; ++h)
#pragma unroll
      for (int i = 0; i < 4; ++i)
        rb[h][i] = *reinterpret_cast<const f32x4*>(bdp + (size_t)(k + 32 * h + i) * HDIM);
  };
  auto writeB = [&]() {
#pragma unroll
    for (int h = 0; h < 2; ++h)
#pragma unroll
      for (int c = 0; c < 4; ++c) {
        u16x4 tb;
#pragma unroll
        for (int i = 0; i < 4; ++i) tb[i] = f2b(rb[h][i][c]);
        *reinterpret_cast<u16x4*>(Bs + swzh(nq4 + c, (kg4 + 32 * h) * 2)) = tb;
      }
  };
  auto compute = [&](int abuf) {
#pragma unroll
    for (int ks = 0; ks < 2; ++ks) {
      const int kb = ks * 64 + fk * 16;
      bf16x8 a[4], b[4];
#pragma unroll
      for (int mi = 0; mi < 4; ++mi)
        a[mi] = *reinterpret_cast<const bf16x8*>(As + abuf + swzh(wm + mi * 16 + fr, kb));
#pragma unroll
      for (int ni = 0; ni < 4; ++ni)
        b[ni] = *reinterpret_cast<const bf16x8*>(Bs + swzh(wn + ni * 16 + fr, kb));
      __builtin_amdgcn_s_setprio(1);
#pragma unroll
      for (int mi = 0; mi < 4; ++mi)
#pragma unroll
        for (int ni = 0; ni < 4; ++ni)
          acc[mi][ni] = __builtin_amdgcn_mfma_f32_16x16x32_bf16(a[mi], b[ni], acc[mi][ni], 0, 0, 0);
      __builtin_amdgcn_s_setprio(0);
    }
  };

  stageA(0, 0);
  stageA(64, 16384);
  loadB(0);
  WAIT_VM0();
  writeB();
  WAIT_LGKM0();
  BARRIER();
  loadB(64);

  const int NT = IDIM / 64;  // 16
#pragma unroll 1
  for (int t = 0; t < NT; ++t) {
    compute((t & 1) * 16384);
    WAIT_LGKM0();
    BARRIER();
    if (t + 1 < NT) {
      WAIT_VM0();
      writeB();
    }
    if (t + 2 < NT) stageA((t + 2) * 64, (t & 1) * 16384);
    WAIT_LGKM0();
    BARRIER();
    if (t + 2 < NT) loadB((t + 2) * 64);
  }

#pragma unroll
  for (int mi = 0; mi < 4; ++mi)
#pragma unroll
    for (int ni = 0; ni < 4; ++ni)
#pragma unroll
      for (int r = 0; r < 4; ++r) {
        const int trow = wm + mi * 16 + fk * 4 + r;
        if (m0 + trow < cnt) {
          const int t = slot_s[trow] >> 1;
          const int col = n0 + wn + ni * 16 + fr;
          atomicAdd(&out[(size_t)t * HDIM + col], acc[mi][ni][r]);
        }
      }
}

// ---------------------------------------------------------------- launch
extern "C" void kernel_launch(void* const* d_in, const int* in_sizes, int n_in,
                              void* d_out, int out_size, void* d_ws, size_t ws_size,
                              hipStream_t stream) {
  const float* x = (const float*)d_in[0];
  const float* gate_w = (const float*)d_in[1];
  const float* wg = (const float*)d_in[2];
  const float* wu = (const float*)d_in[3];
  const float* wd = (const float*)d_in[4];
  float* out = (float*)d_out;

  char* w = (char*)d_ws;
  size_t off = 0;
  unsigned short* xb = (unsigned short*)(w + off); off += (size_t)TTOK * HDIM * 2;
  unsigned short* act = (unsigned short*)(w + off); off += (size_t)TTOK * KTOP * IDIM * 2;
  float* tw = (float*)(w + off); off += (size_t)TTOK * KTOP * 4;
  int2* tidx = (int2*)(w + off); off += (size_t)TTOK * 8;
  int* counts = (int*)(w + off); off += 256;
  int* list = (int*)(w + off); off += (size_t)NEXP * TTOK * 4;

  hipMemsetAsync(out, 0, (size_t)TTOK * HDIM * sizeof(float), stream);
  gating_kernel<<<TTOK / 4, 256, 0, stream>>>(x, gate_w, xb, tw, tidx);
  build_lists_kernel<<<1, 1024, 0, stream>>>(tidx, counts, list);
  // gemm1: 16 e x 8 m x 8 n = 1024 blocks (XCD-clustered decode in-kernel)
  gemm1_kernel<<<1024, 512, 0, stream>>>(xb, wg, wu, counts, list, tw, act);
  // gemm2: 16 e x 8 m x 8 n = 1024 blocks
  gemm2_kernel<<<1024, 512, 0, stream>>>(act, wd, counts, list, out);
}

// Round 20
// 314.336 us; speedup vs baseline: 2.7862x; 1.3398x over previous
//
#include <hip/hip_runtime.h>
#include <hip/hip_bf16.h>

#define HDIM 2048
#define IDIM 1024
#define NEXP 16
#define TTOK 4096   // B*S tokens
#define KTOP 2

typedef __attribute__((ext_vector_type(4))) float f32x4;
typedef __attribute__((ext_vector_type(8))) short bf16x8;
typedef __attribute__((ext_vector_type(4))) unsigned short u16x4;

__device__ __forceinline__ unsigned short f2b(float f) {
  __hip_bfloat16 h = __float2bfloat16(f);
  return *reinterpret_cast<unsigned short*>(&h);
}

// phase-boundary primitives
#define WAIT_VM0()   { asm volatile("s_waitcnt vmcnt(0)" ::: "memory"); __builtin_amdgcn_sched_barrier(0); }
#define WAIT_LGKM0() { asm volatile("s_waitcnt lgkmcnt(0)" ::: "memory"); __builtin_amdgcn_sched_barrier(0); }
#define BARRIER()    { __builtin_amdgcn_s_barrier(); __builtin_amdgcn_sched_barrier(0); }

// byte offset in a [rows][64 bf16] LDS tile (128 B/row), hash-swizzled.
__device__ __forceinline__ int swzh(int row, int kb) {
  return row * 128 + (kb ^ (((row ^ (row >> 3)) & 7) << 4));
}
__device__ __forceinline__ int rowhash(int r) { return (r ^ (r >> 3)) & 7; }

// ---------------------------------------------------------------- gating + x->bf16 (fused)
__global__ __launch_bounds__(256) void gating_kernel(const float* __restrict__ x,
                                                     const float* __restrict__ gw,
                                                     unsigned short* __restrict__ xb,
                                                     float* __restrict__ tw,
                                                     int2* __restrict__ tidx) {
  const int wv = threadIdx.x >> 6;
  const int lane = threadIdx.x & 63;
  const int t = blockIdx.x * 4 + wv;

  float acc[NEXP];
#pragma unroll
  for (int e = 0; e < NEXP; ++e) acc[e] = 0.f;

  const float* xr = x + (size_t)t * HDIM;
  unsigned short* xbr = xb + (size_t)t * HDIM;
#pragma unroll
  for (int j = 0; j < HDIM / 256; ++j) {
    f32x4 xv = *reinterpret_cast<const f32x4*>(xr + j * 256 + lane * 4);
    u16x4 o;
    o[0] = f2b(xv[0]); o[1] = f2b(xv[1]); o[2] = f2b(xv[2]); o[3] = f2b(xv[3]);
    *reinterpret_cast<u16x4*>(xbr + j * 256 + lane * 4) = o;
#pragma unroll
    for (int e = 0; e < NEXP; ++e) {
      f32x4 gv = *reinterpret_cast<const f32x4*>(gw + (size_t)e * HDIM + j * 256 + lane * 4);
      acc[e] = fmaf(xv[0], gv[0], acc[e]);
      acc[e] = fmaf(xv[1], gv[1], acc[e]);
      acc[e] = fmaf(xv[2], gv[2], acc[e]);
      acc[e] = fmaf(xv[3], gv[3], acc[e]);
    }
  }
#pragma unroll
  for (int e = 0; e < NEXP; ++e) {
#pragma unroll
    for (int off = 32; off; off >>= 1) acc[e] += __shfl_xor(acc[e], off);
  }
  // top-2 (ties -> lowest index, matching lax.top_k)
  int i0 = 0; float s0 = acc[0];
#pragma unroll
  for (int e = 1; e < NEXP; ++e) { if (acc[e] > s0) { s0 = acc[e]; i0 = e; } }
  int i1 = -1; float s1 = -1e30f;
#pragma unroll
  for (int e = 0; e < NEXP; ++e) { if (e != i0 && acc[e] > s1) { s1 = acc[e]; i1 = e; } }

  if (lane == 0) {
    float r = __expf(s1 - s0);          // <= 1
    float w0 = 1.f / (1.f + r);
    float w1 = r / (1.f + r);
    tw[t * 2 + 0] = w0;
    tw[t * 2 + 1] = w1;
    tidx[t] = make_int2(i0, i1);
  }
}

// ---------------------------------------------------------------- build lists
__global__ __launch_bounds__(1024) void build_lists_kernel(const int2* __restrict__ tidx,
                                                           int* __restrict__ counts,
                                                           int* __restrict__ list) {
  __shared__ int cur[NEXP];
  const int tid = threadIdx.x;
  if (tid < NEXP) cur[tid] = 0;
  __syncthreads();
  for (int t = tid; t < TTOK; t += 1024) {
    int2 ii = tidx[t];
    int p = atomicAdd(&cur[ii.x], 1);
    list[ii.x * TTOK + p] = t * 2;
    int q = atomicAdd(&cur[ii.y], 1);
    list[ii.y * TTOK + q] = t * 2 + 1;
  }
  __syncthreads();
  if (tid < NEXP) counts[tid] = cur[tid];
}

// ---------------------------------------------------------------- GEMM1  (BM=128, BN=64, BK=64)
// act[slot, :] = silu(x@wg) * (x@wu) * weight   (measured-best R14/R17 config)
__global__ __launch_bounds__(256, 3) void gemm1_kernel(
    const unsigned short* __restrict__ xb, const float* __restrict__ wg,
    const float* __restrict__ wu, const int* __restrict__ counts,
    const int* __restrict__ list, const float* __restrict__ tw,
    unsigned short* __restrict__ act) {
  const int bid = blockIdx.x;
  const int e = (bid & 7) + 8 * ((bid >> 3) & 1);
  const int rest = bid >> 4;               // 0..127
  const int mblk = rest & 7;
  const int nblk = rest >> 3;              // 0..15
  const int cnt = counts[e];
  const int m0 = mblk * 128;
  if (m0 >= cnt) return;
  const int n0 = nblk * 64;

  __shared__ __align__(16) char As[2 * 128 * 128];  // 2 x [128 m][64 k] bf16, 32 KB
  __shared__ __align__(16) char Bgs[64 * 128];      // [64 n][64 k] bf16, 8 KB
  __shared__ __align__(16) char Bus[64 * 128];
  __shared__ int slot_s[128];
  __shared__ float ws_s[128];

  const int tid = threadIdx.x;
  if (tid < 128) {
    int mr = m0 + tid;
    int mrc = mr < cnt ? mr : cnt - 1;
    int slot = list[e * TTOK + mrc];
    slot_s[tid] = slot;
    ws_s[tid] = tw[slot];
  }
  __syncthreads();

  const int lane = tid & 63;
  const int wv = tid >> 6;

  const unsigned short* agsrc[4];
#pragma unroll
  for (int i = 0; i < 4; ++i) {
    const int r = i * 32 + wv * 8 + (lane >> 3);
    agsrc[i] = xb + (size_t)(slot_s[r] >> 1) * HDIM + ((lane & 7) ^ rowhash(r)) * 8;
  }
  const int adst = wv * 8 * 128;

  const int nq4 = (tid & 15) * 4;
  const int kg4 = (tid >> 4) * 4;
  const float* bgp = wg + (size_t)e * (HDIM * IDIM) + (size_t)kg4 * IDIM + n0 + nq4;
  const float* bup = wu + (size_t)e * (HDIM * IDIM) + (size_t)kg4 * IDIM + n0 + nq4;

  const int wm = (wv >> 1) * 64;
  const int wn = (wv & 1) * 32;
  const int fr = lane & 15;
  const int fk = lane >> 4;

  f32x4 accg[4][2], accu[4][2];
#pragma unroll
  for (int mi = 0; mi < 4; ++mi)
#pragma unroll
    for (int ni = 0; ni < 2; ++ni) {
      accg[mi][ni] = (f32x4){0.f, 0.f, 0.f, 0.f};
      accu[mi][ni] = (f32x4){0.f, 0.f, 0.f, 0.f};
    }

  f32x4 rg[4], ru[4];
  auto stageA = [&](int kelem, int bufo) {
#pragma unroll
    for (int i = 0; i < 4; ++i)
      __builtin_amdgcn_global_load_lds(
          (const __attribute__((address_space(1))) unsigned int*)(agsrc[i] + kelem),
          (__attribute__((address_space(3))) unsigned int*)(As + bufo + adst + i * 4096),
          16, 0, 0);
  };
  auto loadB = [&](int k) {
#pragma unroll
    for (int i = 0; i < 4; ++i) {
      rg[i] = *reinterpret_cast<const f32x4*>(bgp + (size_t)(k + i) * IDIM);
      ru[i] = *reinterpret_cast<const f32x4*>(bup + (size_t)(k + i) * IDIM);
    }
  };
  auto writeB = [&]() {
#pragma unroll
    for (int c = 0; c < 4; ++c) {
      u16x4 tg, tu;
#pragma unroll
      for (int i = 0; i < 4; ++i) { tg[i] = f2b(rg[i][c]); tu[i] = f2b(ru[i][c]); }
      const int wb = swzh(nq4 + c, kg4 * 2);
      *reinterpret_cast<u16x4*>(Bgs + wb) = tg;
      *reinterpret_cast<u16x4*>(Bus + wb) = tu;
    }
  };
  auto compute = [&](int abuf) {
#pragma unroll
    for (int ks = 0; ks < 2; ++ks) {
      const int kb = ks * 64 + fk * 16;
      bf16x8 a[4], bg[2], bu[2];
#pragma unroll
      for (int mi = 0; mi < 4; ++mi)
        a[mi] = *reinterpret_cast<const bf16x8*>(As + abuf + swzh(wm + mi * 16 + fr, kb));
#pragma unroll
      for (int ni = 0; ni < 2; ++ni) {
        bg[ni] = *reinterpret_cast<const bf16x8*>(Bgs + swzh(wn + ni * 16 + fr, kb));
        bu[ni] = *reinterpret_cast<const bf16x8*>(Bus + swzh(wn + ni * 16 + fr, kb));
      }
      __builtin_amdgcn_s_setprio(1);
#pragma unroll
      for (int mi = 0; mi < 4; ++mi)
#pragma unroll
        for (int ni = 0; ni < 2; ++ni) {
          accg[mi][ni] = __builtin_amdgcn_mfma_f32_16x16x32_bf16(a[mi], bg[ni], accg[mi][ni], 0, 0, 0);
          accu[mi][ni] = __builtin_amdgcn_mfma_f32_16x16x32_bf16(a[mi], bu[ni], accu[mi][ni], 0, 0, 0);
        }
      __builtin_amdgcn_s_setprio(0);
    }
  };

  stageA(0, 0);
  stageA(64, 16384);
  loadB(0);
  WAIT_VM0();
  writeB();
  WAIT_LGKM0();
  BARRIER();
  loadB(64);

  const int NT = HDIM / 64;  // 32
#pragma unroll 1
  for (int t = 0; t < NT; ++t) {
    compute((t & 1) * 16384);
    WAIT_LGKM0();
    BARRIER();
    if (t + 1 < NT) {
      WAIT_VM0();
      writeB();
    }
    if (t + 2 < NT) stageA((t + 2) * 64, (t & 1) * 16384);
    WAIT_LGKM0();
    BARRIER();
    if (t + 2 < NT) loadB((t + 2) * 64);
  }

#pragma unroll
  for (int mi = 0; mi < 4; ++mi)
#pragma unroll
    for (int ni = 0; ni < 2; ++ni)
#pragma unroll
      for (int r = 0; r < 4; ++r) {
        const int trow = wm + mi * 16 + fk * 4 + r;
        if (m0 + trow < cnt) {
          const int col = n0 + wn + ni * 16 + fr;
          const float g = accg[mi][ni][r];
          const float u = accu[mi][ni][r];
          const float a = (g / (1.f + __expf(-g))) * u * ws_s[trow];
          act[(size_t)slot_s[trow] * IDIM + col] = f2b(a);
        }
      }
}

// ---------------------------------------------------------------- GEMM2  (BM=128, BN=128, BK=64)
// out[token, :] += act[slot, :] @ wd[e]  (atomics on distinct addresses)
__global__ __launch_bounds__(256, 3) void gemm2_kernel(
    const unsigned short* __restrict__ act, const float* __restrict__ wd,
    const int* __restrict__ counts, const int* __restrict__ list,
    float* __restrict__ out) {
  const int bid = blockIdx.x;
  const int e = (bid & 7) + 8 * ((bid >> 3) & 1);
  const int rest = bid >> 4;               // 0..127
  const int mblk = rest & 7;
  const int nblk = rest >> 3;              // 0..15
  const int cnt = counts[e];
  const int m0 = mblk * 128;
  if (m0 >= cnt) return;
  const int n0 = nblk * 128;

  __shared__ __align__(16) char As[2 * 128 * 128];  // 32 KB
  __shared__ __align__(16) char Bs[128 * 128];      // [128 n][64 k], 16 KB
  __shared__ int slot_s[128];

  const int tid = threadIdx.x;
  if (tid < 128) {
    int mr = m0 + tid;
    int mrc = mr < cnt ? mr : cnt - 1;
    slot_s[tid] = list[e * TTOK + mrc];
  }
  __syncthreads();

  const int lane = tid & 63;
  const int wv = tid >> 6;

  const unsigned short* agsrc[4];
#pragma unroll
  for (int i = 0; i < 4; ++i) {
    const int r = i * 32 + wv * 8 + (lane >> 3);
    agsrc[i] = act + (size_t)slot_s[r] * IDIM + ((lane & 7) ^ rowhash(r)) * 8;
  }
  const int adst = wv * 8 * 128;

  const int nq4 = (tid & 31) * 4;          // n 0..127
  const int kg4 = (tid >> 5) * 4;          // k 0..31 (+32 for h=1)
  const float* bdp = wd + (size_t)e * (IDIM * HDIM) + (size_t)kg4 * HDIM + n0 + nq4;

  const int wm = (wv >> 1) * 64;
  const int wn = (wv & 1) * 64;
  const int fr = lane & 15;
  const int fk = lane >> 4;

  f32x4 acc[4][4];
#pragma unroll
  for (int mi = 0; mi < 4; ++mi)
#pragma unroll
    for (int ni = 0; ni < 4; ++ni) acc[mi][ni] = (f32x4){0.f, 0.f, 0.f, 0.f};

  f32x4 rb[2][4];
  auto stageA = [&](int kelem, int bufo) {
#pragma unroll
    for (int i = 0; i < 4; ++i)
      __builtin_amdgcn_global_load_lds(
          (const __attribute__((address_space(1))) unsigned int*)(agsrc[i] + kelem),
          (__attribute__((address_space(3))) unsigned int*)(As + bufo + adst + i * 4096),
          16, 0, 0);
  };
  auto loadB = [&](int k) {
#pragma unroll
    for (int h = 0; h < 2; ++h)
#pragma unroll
      for (int i = 0; i < 4; ++i)
        rb[h][i] = *reinterpret_cast<const f32x4*>(bdp + (size_t)(k + 32 * h + i) * HDIM);
  };
  auto writeB = [&]() {
#pragma unroll
    for (int h = 0; h < 2; ++h)
#pragma unroll
      for (int c = 0; c < 4; ++c) {
        u16x4 tb;
#pragma unroll
        for (int i = 0; i < 4; ++i) tb[i] = f2b(rb[h][i][c]);
        *reinterpret_cast<u16x4*>(Bs + swzh(nq4 + c, (kg4 + 32 * h) * 2)) = tb;
      }
  };
  auto compute = [&](int abuf) {
#pragma unroll
    for (int ks = 0; ks < 2; ++ks) {
      const int kb = ks * 64 + fk * 16;
      bf16x8 a[4], b[4];
#pragma unroll
      for (int mi = 0; mi < 4; ++mi)
        a[mi] = *reinterpret_cast<const bf16x8*>(As + abuf + swzh(wm + mi * 16 + fr, kb));
#pragma unroll
      for (int ni = 0; ni < 4; ++ni)
        b[ni] = *reinterpret_cast<const bf16x8*>(Bs + swzh(wn + ni * 16 + fr, kb));
      __builtin_amdgcn_s_setprio(1);
#pragma unroll
      for (int mi = 0; mi < 4; ++mi)
#pragma unroll
        for (int ni = 0; ni < 4; ++ni)
          acc[mi][ni] = __builtin_amdgcn_mfma_f32_16x16x32_bf16(a[mi], b[ni], acc[mi][ni], 0, 0, 0);
      __builtin_amdgcn_s_setprio(0);
    }
  };

  stageA(0, 0);
  stageA(64, 16384);
  loadB(0);
  WAIT_VM0();
  writeB();
  WAIT_LGKM0();
  BARRIER();
  loadB(64);

  const int NT = IDIM / 64;  // 16
#pragma unroll 1
  for (int t = 0; t < NT; ++t) {
    compute((t & 1) * 16384);
    WAIT_LGKM0();
    BARRIER();
    if (t + 1 < NT) {
      WAIT_VM0();
      writeB();
    }
    if (t + 2 < NT) stageA((t + 2) * 64, (t & 1) * 16384);
    WAIT_LGKM0();
    BARRIER();
    if (t + 2 < NT) loadB((t + 2) * 64);
  }

#pragma unroll
  for (int mi = 0; mi < 4; ++mi)
#pragma unroll
    for (int ni = 0; ni < 4; ++ni)
#pragma unroll
      for (int r = 0; r < 4; ++r) {
        const int trow = wm + mi * 16 + fk * 4 + r;
        if (m0 + trow < cnt) {
          const int t = slot_s[trow] >> 1;
          const int col = n0 + wn + ni * 16 + fr;
          atomicAdd(&out[(size_t)t * HDIM + col], acc[mi][ni][r]);
        }
      }
}

// ---------------------------------------------------------------- launch
extern "C" void kernel_launch(void* const* d_in, const int* in_sizes, int n_in,
                              void* d_out, int out_size, void* d_ws, size_t ws_size,
                              hipStream_t stream) {
  const float* x = (const float*)d_in[0];
  const float* gate_w = (const float*)d_in[1];
  const float* wg = (const float*)d_in[2];
  const float* wu = (const float*)d_in[3];
  const float* wd = (const float*)d_in[4];
  float* out = (float*)d_out;

  char* w = (char*)d_ws;
  size_t off = 0;
  unsigned short* xb = (unsigned short*)(w + off); off += (size_t)TTOK * HDIM * 2;
  unsigned short* act = (unsigned short*)(w + off); off += (size_t)TTOK * KTOP * IDIM * 2;
  float* tw = (float*)(w + off); off += (size_t)TTOK * KTOP * 4;
  int2* tidx = (int2*)(w + off); off += (size_t)TTOK * 8;
  int* counts = (int*)(w + off); off += 256;
  int* list = (int*)(w + off); off += (size_t)NEXP * TTOK * 4;

  hipMemsetAsync(out, 0, (size_t)TTOK * HDIM * sizeof(float), stream);
  gating_kernel<<<TTOK / 4, 256, 0, stream>>>(x, gate_w, xb, tw, tidx);
  build_lists_kernel<<<1, 1024, 0, stream>>>(tidx, counts, list);
  // gemm1: 16 e x 8 m x 16 n = 2048 blocks (XCD-clustered decode in-kernel)
  gemm1_kernel<<<2048, 256, 0, stream>>>(xb, wg, wu, counts, list, tw, act);
  // gemm2: 16 e x 8 m x 16 n = 2048 blocks
  gemm2_kernel<<<2048, 256, 0, stream>>>(act, wd, counts, list, out);
}